// Round 1
// baseline (35.064 us; speedup 1.0000x reference)
//
#include <hip/hip_runtime.h>

#define N_ROWS 4096
#define N_COLS 10000
#define K_DC   64
#define NTHR   256
#define RPB    2                          // rows per block
#define NBLK   (N_ROWS / RPB)             // 2048 blocks = one full residency round
#define ELEMS  (RPB * N_COLS)             // 20000 floats per block (80 KB)
#define VECS   (ELEMS / 4)                // 5000 float4 per block
#define MASK_WORDS (ELEMS / 32)           // 625 u32 = 2.5 KB LDS bitmap

// Block b streams rows [2b,2b+1] as a PURE sum-of-squares loop (load + 4 FMA,
// no per-vec mask test -- the old nibble check made ~81% of wave-iterations
// diverge into a ~30-instr masked body, throttling load issue). Corrections
// for the <=130 special elems/block are applied in an epilogue that re-gathers
// them from the just-streamed (L1/L2/L3-hot) lines, guided by the LDS bitmap
// (which still provides dedupe + target-over-dont_care precedence for free).
__global__ __launch_bounds__(NTHR) void dcl_partial(
    const float* __restrict__ input,
    const int* __restrict__ target,
    const int* __restrict__ dont_care,
    float* __restrict__ partials)
{
    const int b   = blockIdx.x;
    const int tid = threadIdx.x;

    __shared__ unsigned mask[MASK_WORDS];
    __shared__ int trow[RPB];

    // Issue the special-index loads up front (results consumed only after the
    // stream; compiler issues early, waits late) and zero the bitmap.
    int dc_c = 0;
    if (tid < RPB * K_DC)
        dc_c = dont_care[(b * RPB + (tid >> 6)) * K_DC + (tid & 63)];
    if (tid < RPB)
        trow[tid] = target[b * RPB + tid];
    for (int w = tid; w < MASK_WORDS; w += NTHR)
        mask[w] = 0u;

    // ---- pure stream: 4 independent float4 loads/iter, nothing else ----
    float a0 = 0.f, a1 = 0.f, a2 = 0.f, a3 = 0.f;
    const float4* __restrict__ chunk =
        (const float4*)input + (long long)b * VECS;

    int i = tid;
    for (; i + 3 * NTHR < VECS; i += 4 * NTHR) {
        float4 v0 = chunk[i];
        float4 v1 = chunk[i +     NTHR];
        float4 v2 = chunk[i + 2 * NTHR];
        float4 v3 = chunk[i + 3 * NTHR];
        a0 += v0.x * v0.x + v0.y * v0.y + v0.z * v0.z + v0.w * v0.w;
        a1 += v1.x * v1.x + v1.y * v1.y + v1.z * v1.z + v1.w * v1.w;
        a2 += v2.x * v2.x + v2.y * v2.y + v2.z * v2.z + v2.w * v2.w;
        a3 += v3.x * v3.x + v3.y * v3.y + v3.z * v3.z + v3.w * v3.w;
    }
    for (; i < VECS; i += NTHR) {
        float4 v = chunk[i];
        a0 += v.x * v.x + v.y * v.y + v.z * v.z + v.w * v.w;
    }

    float acc = (a0 + a1) + (a2 + a3);

    // ---- build bitmap (zeroing + trow stores happened pre-stream) ----
    __syncthreads();
    if (tid < RPB * K_DC) {
        const int w = tid >> 6;                         // row-in-block (K_DC=64)
        const int bitpos = w * N_COLS + dc_c;
        atomicOr(&mask[bitpos >> 5], 1u << (bitpos & 31));
    } else if (tid < RPB * K_DC + RPB) {
        const int w = tid - RPB * K_DC;
        const int bitpos = w * N_COLS + trow[w];
        atomicOr(&mask[bitpos >> 5], 1u << (bitpos & 31));
    }
    __syncthreads();

    // ---- epilogue: scan 625 words (2-3/thread), re-gather specials (hot) ----
    const float* __restrict__ base = input + (long long)b * ELEMS;
    for (int w = tid; w < MASK_WORDS; w += NTHR) {
        unsigned m = mask[w];
        while (m) {
            const int bit = __ffs(m) - 1;
            m &= m - 1;
            const int bitpos = w * 32 + bit;
            const int r = (bitpos >= N_COLS) ? 1 : 0;
            const int c = bitpos - r * N_COLS;
            const float x = base[bitpos];               // L1/L2/L3-resident
            if (c == trow[r])
                acc += (1.f - x) * (1.f - x) - x * x;   // target: x^2 -> (1-x)^2
            else
                acc -= x * x;                           // dont_care: x^2 -> 0
        }
    }

    // ---- wave reduction (64-wide) ----
    const int lane = tid & 63;
    #pragma unroll
    for (int off = 32; off > 0; off >>= 1)
        acc += __shfl_down(acc, off, 64);

    // ---- cross-wave via LDS, one plain store per block ----
    __shared__ float warp_sums[NTHR / 64];
    if (lane == 0) warp_sums[tid >> 6] = acc;
    __syncthreads();
    if (tid == 0) {
        partials[b] = (warp_sums[0] + warp_sums[1]) +
                      (warp_sums[2] + warp_sums[3]);
    }
}

// Kernel 2: reduce 2048 partials -> out[0] (plain store, idempotent).
__global__ __launch_bounds__(NTHR) void dcl_reduce(
    const float* __restrict__ partials,
    float* __restrict__ out)
{
    const float4* __restrict__ p4 = (const float4*)partials;
    float s = 0.f;
    #pragma unroll
    for (int i = threadIdx.x; i < NBLK / 4; i += NTHR) {   // 512 float4
        float4 v = p4[i];
        s += (v.x + v.y) + (v.z + v.w);
    }
    #pragma unroll
    for (int off = 32; off > 0; off >>= 1)
        s += __shfl_down(s, off, 64);
    __shared__ float warp_sums[NTHR / 64];
    const int lane = threadIdx.x & 63;
    if (lane == 0) warp_sums[threadIdx.x >> 6] = s;
    __syncthreads();
    if (threadIdx.x == 0)
        out[0] = (warp_sums[0] + warp_sums[1]) + (warp_sums[2] + warp_sums[3]);
}

extern "C" void kernel_launch(void* const* d_in, const int* in_sizes, int n_in,
                              void* d_out, int out_size, void* d_ws, size_t ws_size,
                              hipStream_t stream)
{
    const float* input     = (const float*)d_in[0];
    const int*   target    = (const int*)d_in[1];    // harness passes ints as int32
    const int*   dont_care = (const int*)d_in[2];
    float* out      = (float*)d_out;
    float* partials = (float*)d_ws;                  // 2048 floats = 8 KB scratch

    dcl_partial<<<NBLK, NTHR, 0, stream>>>(input, target, dont_care, partials);
    dcl_reduce<<<1, NTHR, 0, stream>>>(partials, out);
}